// Round 6
// baseline (488.363 us; speedup 1.0000x reference)
//
#include <hip/hip_runtime.h>
#include <hip/hip_bf16.h>
#include <stdint.h>

typedef __hip_bfloat16 bf16;
typedef __attribute__((ext_vector_type(8))) short short8;
typedef __attribute__((ext_vector_type(4))) float floatx4;

__device__ __forceinline__ void gll16(const bf16* g, const bf16* lds_base) {
  __builtin_amdgcn_global_load_lds(
      (const __attribute__((address_space(1))) unsigned int*)g,
      (__attribute__((address_space(3))) unsigned int*)lds_base,
      16, 0, 0);
}

__device__ __forceinline__ unsigned pk2(float a, float b) {
  union { __hip_bfloat16 h; unsigned short u; } ca, cb;
  ca.h = __float2bfloat16(a);
  cb.h = __float2bfloat16(b);
  return (unsigned)ca.u | ((unsigned)cb.u << 16);
}

// ------------- fused transpose+convert for all four weights -------------
// Wq(768x768)->WqT; Wk(4096x768)->WkvT[0:768]; Wv->WkvT[768:1536]; Wo(768x4096)->WoT
__global__ __launch_bounds__(256) void trans_all(const float* __restrict__ Wq,
                                                 const float* __restrict__ Wk,
                                                 const float* __restrict__ Wv,
                                                 const float* __restrict__ Wo,
                                                 bf16* __restrict__ WqT,
                                                 bf16* __restrict__ WkvT,
                                                 bf16* __restrict__ WoT) {
  __shared__ float t[32][33];
  int id = blockIdx.x;
  const float* in; bf16* out; int R, C, cx, ry;
  if (id < 576)        { in = Wq; out = WqT; R = 768;  C = 768;  id -= 0;    cx = id % 24;  ry = id / 24; }
  else if (id < 3648)  { in = Wk; out = WkvT; R = 4096; C = 768; id -= 576;  cx = id % 24;  ry = id / 24; }
  else if (id < 6720)  { in = Wv; out = WkvT + (size_t)768 * 4096; R = 4096; C = 768; id -= 3648; cx = id % 24; ry = id / 24; }
  else                 { in = Wo; out = WoT; R = 768;  C = 4096; id -= 6720; cx = id % 128; ry = id / 128; }
  int tx = threadIdx.x & 31, ty = threadIdx.x >> 5;
  int c0 = cx * 32, r0 = ry * 32;
#pragma unroll
  for (int j = 0; j < 4; ++j)
    t[ty + j * 8][tx] = in[(size_t)(r0 + ty + j * 8) * C + c0 + tx];
  __syncthreads();
#pragma unroll
  for (int j = 0; j < 4; ++j)
    out[(size_t)(c0 + ty + j * 8) * R + r0 + tx] = __float2bfloat16(t[tx][ty + j * 8]);
}

// ---------------- GEMM: C(MxN) = A(MxK) * BT(NxK)^T + bias ----------------
// BM = 128 (wave tile 64x64, acc 4x4) or 64 (wave tile 32x64, acc 2x4).
// A_F32: A is fp32 in global; staged via reg-load + pk2 + ds_write_b128
// (fuses the old cvt pass into the GEMM). B always bf16 via global_load_lds.
template <int BM, bool OUT_F32, bool A_F32>
__global__ __launch_bounds__(256) void gemm_bt(const void* __restrict__ Ain,
                                               const bf16* __restrict__ BT,
                                               const float* __restrict__ bias,
                                               void* __restrict__ Cv,
                                               int M, int N, int K, int ldc) {
  __shared__ bf16 As[BM * 32];
  __shared__ bf16 Bs[128 * 32];
  const int tid = threadIdx.x;
  const int w = tid >> 6, lane = tid & 63;
  const int ln = lane & 15, quad = lane >> 4;
  const int wm = w >> 1, wn = w & 1;
  const int m0 = blockIdx.x * BM, n0 = blockIdx.y * 128;
  constexpr int MT = BM / 32;   // acc tiles in m per wave
  constexpr int TA = BM / 64;   // staging iterations for A

  floatx4 acc[MT][4] = {};

  for (int k0 = 0; k0 < K; k0 += 32) {
    __syncthreads();
    // B first: get its LDS-DMA in flight before A's register loads
#pragma unroll
    for (int t = 0; t < 2; ++t) {
      int cidb = (w * 2 + t) * 64;
      int cid = cidb + lane;
      int row = cid >> 2, ko = (cid & 3) * 8;
      gll16(BT + (size_t)(n0 + row) * K + k0 + ko, Bs + cidb * 8);
    }
    if constexpr (A_F32) {
      const float* Af = (const float*)Ain;
#pragma unroll
      for (int t = 0; t < TA; ++t) {
        int cid = t * 256 + tid;           // chunk id, 8 bf16 elems each
        int row = cid >> 2, ko = (cid & 3) * 8;
        const float* ap = Af + (size_t)(m0 + row) * K + k0 + ko;
        float4 f0 = *(const float4*)ap;
        float4 f1 = *(const float4*)(ap + 4);
        uint4 uu;
        uu.x = pk2(f0.x, f0.y);
        uu.y = pk2(f0.z, f0.w);
        uu.z = pk2(f1.x, f1.y);
        uu.w = pk2(f1.z, f1.w);
        *(uint4*)(As + (size_t)cid * 8) = uu;
      }
    } else {
      const bf16* Ab = (const bf16*)Ain;
#pragma unroll
      for (int t = 0; t < TA; ++t) {
        int cidb = (w * TA + t) * 64;
        int cid = cidb + lane;
        int row = cid >> 2, ko = (cid & 3) * 8;
        gll16(Ab + (size_t)(m0 + row) * K + k0 + ko, As + cidb * 8);
      }
    }
    __syncthreads();
    const short8* Av = (const short8*)As;
    const short8* Bv = (const short8*)Bs;
    short8 a[MT], b[4];
#pragma unroll
    for (int mt = 0; mt < MT; ++mt) a[mt] = Av[(wm * (BM / 2) + mt * 16 + ln) * 4 + quad];
#pragma unroll
    for (int nt = 0; nt < 4; ++nt) b[nt] = Bv[(wn * 64 + nt * 16 + ln) * 4 + quad];
#pragma unroll
    for (int mt = 0; mt < MT; ++mt)
#pragma unroll
      for (int nt = 0; nt < 4; ++nt)
        acc[mt][nt] = __builtin_amdgcn_mfma_f32_16x16x32_bf16(a[mt], b[nt], acc[mt][nt], 0, 0, 0);
  }

#pragma unroll
  for (int nt = 0; nt < 4; ++nt) {
    int n = n0 + wn * 64 + nt * 16 + ln;
    float bv_ = bias[n];
#pragma unroll
    for (int mt = 0; mt < MT; ++mt)
#pragma unroll
      for (int r = 0; r < 4; ++r) {
        int m = m0 + wm * (BM / 2) + mt * 16 + quad * 4 + r;
        float v = acc[mt][nt][r] + bv_;
        size_t idx = (size_t)m * ldc + n;
        if (OUT_F32)
          ((float*)Cv)[idx] = v;
        else
          ((bf16*)Cv)[idx] = __float2bfloat16(v);
      }
  }
}

// ---------- fused K/V projection, split-K=NS, BM=64: fp32 source read direct ----------
// grid (32, 12, NS) -> 768 blocks at NS=2 = 3 blocks/CU (was 1.5 at BM=128).
template <int NS>
__global__ __launch_bounds__(256) void gemm_kv_splitk(const float* __restrict__ A,
                                                      const bf16* __restrict__ BT,
                                                      float* __restrict__ P) {
  __shared__ bf16 As[64 * 32];
  __shared__ bf16 Bs[128 * 32];
  const int tid = threadIdx.x;
  const int w = tid >> 6, lane = tid & 63;
  const int ln = lane & 15, quad = lane >> 4;
  const int wm = w >> 1, wn = w & 1;
  const int m0 = blockIdx.x * 64, n0 = blockIdx.y * 128;
  constexpr int KSEG = 4096 / NS;
  const int kbeg = blockIdx.z * KSEG;
  float* Pz = P + (size_t)blockIdx.z * 2048 * 1536;

  floatx4 acc[2][4] = {};

  for (int k0 = kbeg; k0 < kbeg + KSEG; k0 += 32) {
    __syncthreads();
#pragma unroll
    for (int t = 0; t < 2; ++t) {
      int cidb = (w * 2 + t) * 64;
      int cid = cidb + lane;
      int row = cid >> 2, ko = (cid & 3) * 8;
      gll16(BT + (size_t)(n0 + row) * 4096 + k0 + ko, Bs + cidb * 8);
    }
    {
      int row = tid >> 2, ko = (tid & 3) * 8;
      const float* ap = A + (size_t)(m0 + row) * 4096 + k0 + ko;
      float4 f0 = *(const float4*)ap;
      float4 f1 = *(const float4*)(ap + 4);
      uint4 uu;
      uu.x = pk2(f0.x, f0.y);
      uu.y = pk2(f0.z, f0.w);
      uu.z = pk2(f1.x, f1.y);
      uu.w = pk2(f1.z, f1.w);
      *(uint4*)(As + (size_t)tid * 8) = uu;
    }
    __syncthreads();
    const short8* Av = (const short8*)As;
    const short8* Bv = (const short8*)Bs;
    short8 a[2], b[4];
#pragma unroll
    for (int mt = 0; mt < 2; ++mt) a[mt] = Av[(wm * 32 + mt * 16 + ln) * 4 + quad];
#pragma unroll
    for (int nt = 0; nt < 4; ++nt) b[nt] = Bv[(wn * 64 + nt * 16 + ln) * 4 + quad];
#pragma unroll
    for (int mt = 0; mt < 2; ++mt)
#pragma unroll
      for (int nt = 0; nt < 4; ++nt)
        acc[mt][nt] = __builtin_amdgcn_mfma_f32_16x16x32_bf16(a[mt], b[nt], acc[mt][nt], 0, 0, 0);
  }

#pragma unroll
  for (int nt = 0; nt < 4; ++nt) {
    int n = n0 + wn * 64 + nt * 16 + ln;
#pragma unroll
    for (int mt = 0; mt < 2; ++mt)
#pragma unroll
      for (int r = 0; r < 4; ++r) {
        int m = m0 + wm * 32 + mt * 16 + quad * 4 + r;
        Pz[(size_t)m * 1536 + n] = acc[mt][nt][r];
      }
  }
}

// ---------- fused split-K reduce: y==0 -> K half (coalesced), y==1 -> V half (transposed) ----------
template <int NS>
__global__ __launch_bounds__(256) void reduce_kv_both(const float* __restrict__ P,
                                                      const float* __restrict__ bk,
                                                      const float* __restrict__ bv,
                                                      bf16* __restrict__ Kws,
                                                      bf16* __restrict__ VTws) {
  __shared__ float t[32][33];
  if (blockIdx.y == 0) {
    int idx = (blockIdx.x * 256 + threadIdx.x) * 4;  // over 2048*768
    int m = idx / 768, n = idx % 768;
    float4 acc = *(const float4*)(bk + n);
#pragma unroll
    for (int z = 0; z < NS; ++z) {
      float4 a = *(const float4*)(P + (size_t)z * 2048 * 1536 + (size_t)m * 1536 + n);
      acc.x += a.x; acc.y += a.y; acc.z += a.z; acc.w += a.w;
    }
    Kws[(size_t)m * 768 + n + 0] = __float2bfloat16(acc.x);
    Kws[(size_t)m * 768 + n + 1] = __float2bfloat16(acc.y);
    Kws[(size_t)m * 768 + n + 2] = __float2bfloat16(acc.z);
    Kws[(size_t)m * 768 + n + 3] = __float2bfloat16(acc.w);
  } else {
    int tx = threadIdx.x & 31, ty = threadIdx.x >> 5;
    int c0 = (blockIdx.x % 24) * 32;   // V col (e), 0..767
    int r0 = (blockIdx.x / 24) * 32;   // m, 0..2047
#pragma unroll
    for (int j = 0; j < 4; ++j) {
      size_t off = (size_t)(r0 + ty + j * 8) * 1536 + 768 + c0 + tx;
      float s = 0.f;
#pragma unroll
      for (int z = 0; z < NS; ++z) s += P[off + (size_t)z * 2048 * 1536];
      t[ty + j * 8][tx] = s;
    }
    __syncthreads();
#pragma unroll
    for (int j = 0; j < 4; ++j) {
      int e = c0 + ty + j * 8;
      VTws[(size_t)e * 2048 + r0 + tx] = __float2bfloat16(t[tx][ty + j * 8] + bv[e]);
    }
  }
}

// ---------------- attention v4 (unchanged) ----------------
// Grid: blockIdx.x = h (-> XCD locality), blockIdx.y = b*8 + qt.
// Waves 2x2; swapped QK -> packed b64 Ps writes; 3 barriers/tile.
__global__ __launch_bounds__(256, 4) void attn_kernel(const bf16* __restrict__ Q,
                                                      const bf16* __restrict__ Kt,
                                                      const bf16* __restrict__ VT,
                                                      bf16* __restrict__ rep) {
  __shared__ __align__(16) bf16 Ks[64 * 13 * 8];   // 13,312 B, padded stride 13 chunks
  __shared__ __align__(16) bf16 Vs[96 * 9 * 8];    // 13,824 B, padded stride 9 chunks
  __shared__ __align__(16) bf16 Ps[64 * 72];       //  9,216 B, rows q, cols s (+8 pad)
  __shared__ float Rs[2][64];                      //    512 B row-sum exchange

  const int tid = threadIdx.x, w = tid >> 6, lane = tid & 63;
  const int ln = lane & 15, quad = lane >> 4;
  const int wq = w >> 1, ws = w & 1;
  const int h = blockIdx.x;             // head -> XCD
  const int yy = blockIdx.y;            // 0..127
  const int b = yy >> 3, qt = yy & 7;

  // ---- Q fragments in registers: wave (wq,*) owns q-rows wq*32..+32 ----
  const bf16* Qg = Q + (size_t)(b * 512 + qt * 64) * 768 + h * 96;
  short8 qf[2][3];
#pragma unroll
  for (int mt = 0; mt < 2; ++mt)
#pragma unroll
    for (int es = 0; es < 3; ++es)
      qf[mt][es] = *(const short8*)(Qg + (size_t)(wq * 32 + mt * 16 + ln) * 768 + (es * 4 + quad) * 8);

  const bf16* Kgh = Kt + h * 96;
  const bf16* Vgh = VT + (size_t)h * 96 * 2048;

  // staging maps: K = 64 rows x 12 chunks; V = 96 rows x 8 chunks (3 chunks/thread each)
  int krow[3], koff[3], vrow[3], voff[3];
#pragma unroll
  for (int t = 0; t < 3; ++t) {
    int cid = t * 256 + tid;
    krow[t] = cid / 12; koff[t] = cid % 12;
    vrow[t] = cid >> 3; voff[t] = cid & 7;
  }

  // prologue: load tile 0 into staging registers
  short8 kreg[3], vreg[3];
#pragma unroll
  for (int t = 0; t < 3; ++t) {
    kreg[t] = *(const short8*)(Kgh + (size_t)krow[t] * 768 + koff[t] * 8);
    vreg[t] = *(const short8*)(Vgh + (size_t)vrow[t] * 2048 + voff[t] * 8);
  }

  floatx4 po[2][3] = {};   // O acc: q-rows wq*32+mt*16+quad*4+r, e = ws*48+nt*16+ln
  float psum[2] = {};      // row-sum partial for q = wq*32+mt*16+ln
  const float cexp = 1.4426950408889634f / 9.797958971132712f;  // log2(e)/sqrt(96)

  for (int it = 0; it < 32; ++it) {
    const int s0 = it * 64;
    __syncthreads();  // (1) all waves done reading Ks/Vs of previous tile

    // write staged tile into LDS
#pragma unroll
    for (int t = 0; t < 3; ++t) {
      *(short8*)(&Ks[(krow[t] * 13 + koff[t]) * 8]) = kreg[t];
      *(short8*)(&Vs[(vrow[t] * 9 + voff[t]) * 8]) = vreg[t];
    }
    // issue next tile's coalesced global loads early (hide under compute)
    if (it < 31) {
#pragma unroll
      for (int t = 0; t < 3; ++t) {
        kreg[t] = *(const short8*)(Kgh + (size_t)(s0 + 64 + krow[t]) * 768 + koff[t] * 8);
        vreg[t] = *(const short8*)(Vgh + (size_t)vrow[t] * 2048 + s0 + 64 + voff[t] * 8);
      }
    }
    __syncthreads();  // (2) LDS tile visible

    // QK^T swapped: sacc[mt][ct] = S^T block [s = ws*32+ct*16+quad*4+r][q = wq*32+mt*16+ln]
    floatx4 sacc[2][2] = {};
    const short8* Kv = (const short8*)Ks;
#pragma unroll
    for (int es = 0; es < 3; ++es) {
      short8 kf[2];
#pragma unroll
      for (int ct = 0; ct < 2; ++ct) kf[ct] = Kv[(ws * 32 + ct * 16 + ln) * 13 + es * 4 + quad];
#pragma unroll
      for (int mt = 0; mt < 2; ++mt)
#pragma unroll
        for (int ct = 0; ct < 2; ++ct)
          sacc[mt][ct] = __builtin_amdgcn_mfma_f32_16x16x32_bf16(kf[ct], qf[mt][es], sacc[mt][ct], 0, 0, 0);
    }

    // exp + pack 4 consecutive-s values -> one b64 write per (mt,ct)
#pragma unroll
    for (int mt = 0; mt < 2; ++mt) {
      float rs = 0.f;
#pragma unroll
      for (int ct = 0; ct < 2; ++ct) {
        float p0 = exp2f(sacc[mt][ct][0] * cexp);
        float p1 = exp2f(sacc[mt][ct][1] * cexp);
        float p2 = exp2f(sacc[mt][ct][2] * cexp);
        float p3 = exp2f(sacc[mt][ct][3] * cexp);
        rs += (p0 + p1) + (p2 + p3);
        uint2 uu;
        uu.x = pk2(p0, p1);
        uu.y = pk2(p2, p3);
        *(uint2*)(Ps + (wq * 32 + mt * 16 + ln) * 72 + ws * 32 + ct * 16 + quad * 4) = uu;
      }
      psum[mt] += rs;
    }
    __syncthreads();  // (3) Ps visible (PV needs both s-halves)

    // PV: O[q][e], A = P rows q (full s), B = V^T rows e
    const short8* Pv = (const short8*)Ps;  // 9 chunks/row
    const short8* Vv = (const short8*)Vs;  // 9 chunks/row
#pragma unroll
    for (int ks = 0; ks < 2; ++ks) {
      short8 pa[2];
#pragma unroll
      for (int mt = 0; mt < 2; ++mt) pa[mt] = Pv[(wq * 32 + mt * 16 + ln) * 9 + ks * 4 + quad];
#pragma unroll
      for (int nt = 0; nt < 3; ++nt) {
        short8 vb = Vv[(ws * 48 + nt * 16 + ln) * 9 + ks * 4 + quad];
#pragma unroll
        for (int mt = 0; mt < 2; ++mt)
          po[mt][nt] = __builtin_amdgcn_mfma_f32_16x16x32_bf16(pa[mt], vb, po[mt][nt], 0, 0, 0);
      }
    }
  }

  // ---- row sums: quad-combine in-wave, ws-combine via LDS ----
  float t0 = psum[0], t1 = psum[1];
  t0 += __shfl_xor(t0, 16, 64); t0 += __shfl_xor(t0, 32, 64);
  t1 += __shfl_xor(t1, 16, 64); t1 += __shfl_xor(t1, 32, 64);
  if (lane < 16) {
    Rs[ws][wq * 32 + lane] = t0;
    Rs[ws][wq * 32 + 16 + lane] = t1;
  }
  __syncthreads();

  float linv[2][4];
#pragma unroll
  for (int mt = 0; mt < 2; ++mt)
#pragma unroll
    for (int r = 0; r < 4; ++r) {
      int q = wq * 32 + mt * 16 + quad * 4 + r;
      float v = Rs[0][q] + Rs[1][q];
      linv[mt][r] = 1.f / fmaxf(v, 1e-37f);
    }

  bf16* og = rep + (size_t)(b * 512 + qt * 64) * 768 + h * 96;
#pragma unroll
  for (int mt = 0; mt < 2; ++mt)
#pragma unroll
    for (int nt = 0; nt < 3; ++nt)
#pragma unroll
      for (int r = 0; r < 4; ++r) {
        int row = wq * 32 + mt * 16 + quad * 4 + r;
        int e = ws * 48 + nt * 16 + ln;
        og[(size_t)row * 768 + e] = __float2bfloat16(po[mt][nt][r] * linv[mt][r]);
      }
}

extern "C" void kernel_launch(void* const* d_in, const int* in_sizes, int n_in,
                              void* d_out, int out_size, void* d_ws, size_t ws_size,
                              hipStream_t stream) {
  const float* target = (const float*)d_in[0];  // (8192, 768)
  const float* source = (const float*)d_in[1];  // (2048, 4096)
  const float* Wq = (const float*)d_in[2];
  const float* bq = (const float*)d_in[3];
  const float* Wk = (const float*)d_in[4];
  const float* bk = (const float*)d_in[5];
  const float* Wv = (const float*)d_in[6];
  const float* bv = (const float*)d_in[7];
  const float* Wo = (const float*)d_in[8];
  const float* bo = (const float*)d_in[9];
  float* out = (float*)d_out;                   // (8192, 4096) fp32

  // Compact workspace (cvt pass deleted; fp32 A read directly by GEMMs):
  bf16* ws = (bf16*)d_ws;
  bf16* WqT = ws;                       //    589,824
  bf16* WkvT = WqT + 589824;            //  6,291,456
  bf16* WoT = WkvT + 6291456;           //  3,145,728
  bf16* Qws = WoT + 3145728;            //  6,291,456
  bf16* Kws = Qws + 6291456;            //  1,572,864
  bf16* VTws = Kws + 1572864;           //  1,572,864
  bf16* repws = VTws + 1572864;         //  6,291,456
  float* Pkv = (float*)(repws + 6291456);
  const size_t PKV_OFF = 25755648ull * 2;        // 51.5 MB base
  const size_t SEG = 2048ull * 1536 * 4;         // 12.58 MB per split-K segment
  const size_t NEED2 = PKV_OFF + 2 * SEG;        // 76.7 MB

  trans_all<<<9792, 256, 0, stream>>>(Wq, Wk, Wv, Wo, WqT, WkvT, WoT);

  // Q projection: BM=64, fp32 A fused-convert -> 768 blocks (3/CU)
  gemm_bt<64, false, true><<<dim3(128, 6), 256, 0, stream>>>(target, WqT, bq, Qws, 8192, 768, 768, 768);

  if (ws_size >= NEED2) {
    gemm_kv_splitk<2><<<dim3(32, 12, 2), 256, 0, stream>>>(source, WkvT, Pkv);
    reduce_kv_both<2><<<dim3(1536, 2), 256, 0, stream>>>(Pkv, bk, bv, Kws, VTws);
  } else {
    // NS=1: same kernels, single segment (still correct, just less parallel)
    gemm_kv_splitk<1><<<dim3(32, 12, 1), 256, 0, stream>>>(source, WkvT, Pkv);
    reduce_kv_both<1><<<dim3(1536, 2), 256, 0, stream>>>(Pkv, bk, bv, Kws, VTws);
  }

  // grid.x = h (XCD locality for the per-head K/V slice), grid.y = b*8 + qt
  attn_kernel<<<dim3(8, 128), 256, 0, stream>>>(Qws, Kws, VTws, repws);

  gemm_bt<128, true, false><<<dim3(64, 32), 256, 0, stream>>>(repws, WoT, bo, out, 8192, 4096, 768, 4096);
}

// Round 7
// 472.961 us; speedup vs baseline: 1.0326x; 1.0326x over previous
//
#include <hip/hip_runtime.h>
#include <hip/hip_bf16.h>
#include <stdint.h>

typedef __hip_bfloat16 bf16;
typedef __attribute__((ext_vector_type(8))) short short8;
typedef __attribute__((ext_vector_type(4))) float floatx4;

__device__ __forceinline__ void gll16(const bf16* g, const bf16* lds_base) {
  __builtin_amdgcn_global_load_lds(
      (const __attribute__((address_space(1))) unsigned int*)g,
      (__attribute__((address_space(3))) unsigned int*)lds_base,
      16, 0, 0);
}

__device__ __forceinline__ unsigned pk2(float a, float b) {
  union { __hip_bfloat16 h; unsigned short u; } ca, cb;
  ca.h = __float2bfloat16(a);
  cb.h = __float2bfloat16(b);
  return (unsigned)ca.u | ((unsigned)cb.u << 16);
}

// ---------- merged: fp32->bf16 convert (target, source) + weight transposes ----------
// blocks [0,6144): target cvt; [6144,14336): source cvt; [14336,24128): transposes.
__global__ __launch_bounds__(256) void cvt_trans(const float* __restrict__ t_in,
                                                 const float* __restrict__ s_in,
                                                 const float* __restrict__ Wq,
                                                 const float* __restrict__ Wk,
                                                 const float* __restrict__ Wv,
                                                 const float* __restrict__ Wo,
                                                 bf16* __restrict__ t_out,
                                                 bf16* __restrict__ s_out,
                                                 bf16* __restrict__ WqT,
                                                 bf16* __restrict__ WkvT,
                                                 bf16* __restrict__ WoT) {
  __shared__ float t[32][33];
  int bid = blockIdx.x;
  if (bid < 14336) {
    const float* in;
    bf16* out;
    int i;
    if (bid < 6144) { in = t_in; out = t_out; i = (bid * 256 + threadIdx.x) * 4; }
    else            { in = s_in; out = s_out; i = ((bid - 6144) * 256 + threadIdx.x) * 4; }
    float4 v = *(const float4*)(in + i);
    out[i + 0] = __float2bfloat16(v.x);
    out[i + 1] = __float2bfloat16(v.y);
    out[i + 2] = __float2bfloat16(v.z);
    out[i + 3] = __float2bfloat16(v.w);
    return;
  }
  int id = bid - 14336;
  const float* in; bf16* out; int R, C, cx, ry;
  if (id < 576)        { in = Wq; out = WqT; R = 768;  C = 768;  id -= 0;    cx = id % 24;  ry = id / 24; }
  else if (id < 3648)  { in = Wk; out = WkvT; R = 4096; C = 768; id -= 576;  cx = id % 24;  ry = id / 24; }
  else if (id < 6720)  { in = Wv; out = WkvT + (size_t)768 * 4096; R = 4096; C = 768; id -= 3648; cx = id % 24; ry = id / 24; }
  else                 { in = Wo; out = WoT; R = 768;  C = 4096; id -= 6720; cx = id % 128; ry = id / 128; }
  int tx = threadIdx.x & 31, ty = threadIdx.x >> 5;
  int c0 = cx * 32, r0 = ry * 32;
#pragma unroll
  for (int j = 0; j < 4; ++j)
    t[ty + j * 8][tx] = in[(size_t)(r0 + ty + j * 8) * C + c0 + tx];
  __syncthreads();
#pragma unroll
  for (int j = 0; j < 4; ++j)
    out[(size_t)(c0 + ty + j * 8) * R + r0 + tx] = __float2bfloat16(t[tx][ty + j * 8]);
}

// ---------- shared BM=64 GEMM core: As 64x32, Bs 128x32, all-gll16 staging ----------
__device__ __forceinline__ void gemm64_core(const bf16* __restrict__ A,
                                            const bf16* __restrict__ BT,
                                            int K, int kbeg, int kend,
                                            int m0, int n0,
                                            bf16* As, bf16* Bs,
                                            floatx4 acc[2][4]) {
  const int tid = threadIdx.x;
  const int w = tid >> 6, lane = tid & 63;
  const int ln = lane & 15, quad = lane >> 4;
  for (int k0 = kbeg; k0 < kend; k0 += 32) {
    __syncthreads();
#pragma unroll
    for (int t = 0; t < 2; ++t) {
      int cidb = (w * 2 + t) * 64;
      int cid = cidb + lane;
      int row = cid >> 2, ko = (cid & 3) * 8;
      gll16(BT + (size_t)(n0 + row) * K + k0 + ko, Bs + cidb * 8);
    }
    {
      int cidb = w * 64;
      int cid = cidb + lane;
      int row = cid >> 2, ko = (cid & 3) * 8;
      gll16(A + (size_t)(m0 + row) * K + k0 + ko, As + cidb * 8);
    }
    __syncthreads();
    const short8* Av = (const short8*)As;
    const short8* Bv = (const short8*)Bs;
    const int wm = w >> 1, wn = w & 1;
    short8 a[2], b[4];
#pragma unroll
    for (int mt = 0; mt < 2; ++mt) a[mt] = Av[(wm * 32 + mt * 16 + ln) * 4 + quad];
#pragma unroll
    for (int nt = 0; nt < 4; ++nt) b[nt] = Bv[(wn * 64 + nt * 16 + ln) * 4 + quad];
#pragma unroll
    for (int mt = 0; mt < 2; ++mt)
#pragma unroll
      for (int nt = 0; nt < 4; ++nt)
        acc[mt][nt] = __builtin_amdgcn_mfma_f32_16x16x32_bf16(a[mt], b[nt], acc[mt][nt], 0, 0, 0);
  }
}

// ---------- merged Q projection + K/V split-K projection (one dispatch) ----------
// blocks [0,768): Q-proj  (M=8192,K=768 -> Qws bf16, bias bq)
// blocks [768, 768+NS*384): KV split-K (M=2048,K=4096/NS -> Pkv fp32, no bias)
template <int NS>
__global__ __launch_bounds__(256) void qkv_proj(const bf16* __restrict__ tgt,
                                                const bf16* __restrict__ src,
                                                const bf16* __restrict__ WqT,
                                                const bf16* __restrict__ WkvT,
                                                const float* __restrict__ bq,
                                                bf16* __restrict__ Qws,
                                                float* __restrict__ P) {
  __shared__ bf16 As[64 * 32];
  __shared__ bf16 Bs[128 * 32];
  const int tid = threadIdx.x;
  const int w = tid >> 6, lane = tid & 63;
  const int ln = lane & 15, quad = lane >> 4;
  const int wm = w >> 1, wn = w & 1;
  const int id = blockIdx.x;

  floatx4 acc[2][4] = {};

  if (id < 768) {
    // ---- Q projection ----
    const int mb = id & 127, nb = id >> 7;      // 128 x 6
    const int m0 = mb * 64, n0 = nb * 128;
    gemm64_core(tgt, WqT, 768, 0, 768, m0, n0, As, Bs, acc);
#pragma unroll
    for (int nt = 0; nt < 4; ++nt) {
      int n = n0 + wn * 64 + nt * 16 + ln;
      float bv_ = bq[n];
#pragma unroll
      for (int mt = 0; mt < 2; ++mt)
#pragma unroll
        for (int r = 0; r < 4; ++r) {
          int m = m0 + wm * 32 + mt * 16 + quad * 4 + r;
          Qws[(size_t)m * 768 + n] = __float2bfloat16(acc[mt][nt][r] + bv_);
        }
    }
  } else {
    // ---- KV split-K ----
    const int t2 = id - 768;
    const int z = t2 / 384, r2 = t2 % 384;
    const int mb = r2 & 31, nb = r2 >> 5;       // 32 x 12
    const int m0 = mb * 64, n0 = nb * 128;
    constexpr int KSEG = 4096 / NS;
    const int kbeg = z * KSEG;
    float* Pz = P + (size_t)z * 2048 * 1536;
    gemm64_core(src, WkvT, 4096, kbeg, kbeg + KSEG, m0, n0, As, Bs, acc);
#pragma unroll
    for (int nt = 0; nt < 4; ++nt) {
      int n = n0 + wn * 64 + nt * 16 + ln;
#pragma unroll
      for (int mt = 0; mt < 2; ++mt)
#pragma unroll
        for (int r = 0; r < 4; ++r) {
          int m = m0 + wm * 32 + mt * 16 + quad * 4 + r;
          Pz[(size_t)m * 1536 + n] = acc[mt][nt][r];
        }
    }
  }
}

// ---------- fused split-K reduce: y==0 -> K half (coalesced), y==1 -> V half (transposed) ----------
template <int NS>
__global__ __launch_bounds__(256) void reduce_kv_both(const float* __restrict__ P,
                                                      const float* __restrict__ bk,
                                                      const float* __restrict__ bv,
                                                      bf16* __restrict__ Kws,
                                                      bf16* __restrict__ VTws) {
  __shared__ float t[32][33];
  if (blockIdx.y == 0) {
    int idx = (blockIdx.x * 256 + threadIdx.x) * 4;  // over 2048*768
    int m = idx / 768, n = idx % 768;
    float4 acc = *(const float4*)(bk + n);
#pragma unroll
    for (int z = 0; z < NS; ++z) {
      float4 a = *(const float4*)(P + (size_t)z * 2048 * 1536 + (size_t)m * 1536 + n);
      acc.x += a.x; acc.y += a.y; acc.z += a.z; acc.w += a.w;
    }
    Kws[(size_t)m * 768 + n + 0] = __float2bfloat16(acc.x);
    Kws[(size_t)m * 768 + n + 1] = __float2bfloat16(acc.y);
    Kws[(size_t)m * 768 + n + 2] = __float2bfloat16(acc.z);
    Kws[(size_t)m * 768 + n + 3] = __float2bfloat16(acc.w);
  } else {
    int tx = threadIdx.x & 31, ty = threadIdx.x >> 5;
    int c0 = (blockIdx.x % 24) * 32;   // V col (e), 0..767
    int r0 = (blockIdx.x / 24) * 32;   // m, 0..2047
#pragma unroll
    for (int j = 0; j < 4; ++j) {
      size_t off = (size_t)(r0 + ty + j * 8) * 1536 + 768 + c0 + tx;
      float s = 0.f;
#pragma unroll
      for (int z = 0; z < NS; ++z) s += P[off + (size_t)z * 2048 * 1536];
      t[ty + j * 8][tx] = s;
    }
    __syncthreads();
#pragma unroll
    for (int j = 0; j < 4; ++j) {
      int e = c0 + ty + j * 8;
      VTws[(size_t)e * 2048 + r0 + tx] = __float2bfloat16(t[tx][ty + j * 8] + bv[e]);
    }
  }
}

// ---------------- Wo GEMM: 128^2 tile, bf16 A/B via gll16, fp32 out, XCD swizzle ----------------
// 1-D grid 2048; work id -> (bx,by) chunked so each XCD owns 8 m-panels x all n
// (A-chunk 1.6 MB + whole WoT 6.3 MB ~ L2-resident per XCD).
__global__ __launch_bounds__(256) void gemm_wo(const bf16* __restrict__ A,
                                               const bf16* __restrict__ BT,
                                               const float* __restrict__ bias,
                                               float* __restrict__ C) {
  __shared__ bf16 As[128 * 32];
  __shared__ bf16 Bs[128 * 32];
  const int tid = threadIdx.x;
  const int w = tid >> 6, lane = tid & 63;
  const int ln = lane & 15, quad = lane >> 4;
  const int wm = w >> 1, wn = w & 1;
  const int W = blockIdx.x;                 // 0..2047
  const int cid2 = (W & 7) * 256 + (W >> 3);  // XCD chunking (2048 % 8 == 0 -> bijective)
  const int bx = cid2 >> 5, by = cid2 & 31;   // 64 m-blocks x 32 n-blocks
  const int m0 = bx * 128, n0 = by * 128;
  const int K = 768, ldc = 4096;

  floatx4 acc[4][4] = {};

  for (int k0 = 0; k0 < K; k0 += 32) {
    __syncthreads();
#pragma unroll
    for (int t = 0; t < 2; ++t) {
      int cidb = (w * 2 + t) * 64;
      int cid = cidb + lane;
      int row = cid >> 2, ko = (cid & 3) * 8;
      gll16(A + (size_t)(m0 + row) * K + k0 + ko, As + cidb * 8);
      gll16(BT + (size_t)(n0 + row) * K + k0 + ko, Bs + cidb * 8);
    }
    __syncthreads();
    const short8* Av = (const short8*)As;
    const short8* Bv = (const short8*)Bs;
    short8 a[4], b[4];
#pragma unroll
    for (int mt = 0; mt < 4; ++mt) a[mt] = Av[(wm * 64 + mt * 16 + ln) * 4 + quad];
#pragma unroll
    for (int nt = 0; nt < 4; ++nt) b[nt] = Bv[(wn * 64 + nt * 16 + ln) * 4 + quad];
#pragma unroll
    for (int mt = 0; mt < 4; ++mt)
#pragma unroll
      for (int nt = 0; nt < 4; ++nt)
        acc[mt][nt] = __builtin_amdgcn_mfma_f32_16x16x32_bf16(a[mt], b[nt], acc[mt][nt], 0, 0, 0);
  }

#pragma unroll
  for (int nt = 0; nt < 4; ++nt) {
    int n = n0 + wn * 64 + nt * 16 + ln;
    float bv_ = bias[n];
#pragma unroll
    for (int mt = 0; mt < 4; ++mt)
#pragma unroll
      for (int r = 0; r < 4; ++r) {
        int m = m0 + wm * 64 + mt * 16 + quad * 4 + r;
        C[(size_t)m * ldc + n] = acc[mt][nt][r] + bv_;
      }
  }
}

// ---------------- attention v4 (unchanged) ----------------
// Grid: blockIdx.x = h (-> XCD locality), blockIdx.y = b*8 + qt.
// Waves 2x2; swapped QK -> packed b64 Ps writes; 3 barriers/tile.
__global__ __launch_bounds__(256, 4) void attn_kernel(const bf16* __restrict__ Q,
                                                      const bf16* __restrict__ Kt,
                                                      const bf16* __restrict__ VT,
                                                      bf16* __restrict__ rep) {
  __shared__ __align__(16) bf16 Ks[64 * 13 * 8];   // 13,312 B, padded stride 13 chunks
  __shared__ __align__(16) bf16 Vs[96 * 9 * 8];    // 13,824 B, padded stride 9 chunks
  __shared__ __align__(16) bf16 Ps[64 * 72];       //  9,216 B, rows q, cols s (+8 pad)
  __shared__ float Rs[2][64];                      //    512 B row-sum exchange

  const int tid = threadIdx.x, w = tid >> 6, lane = tid & 63;
  const int ln = lane & 15, quad = lane >> 4;
  const int wq = w >> 1, ws = w & 1;
  const int h = blockIdx.x;             // head -> XCD
  const int yy = blockIdx.y;            // 0..127
  const int b = yy >> 3, qt = yy & 7;

  // ---- Q fragments in registers: wave (wq,*) owns q-rows wq*32..+32 ----
  const bf16* Qg = Q + (size_t)(b * 512 + qt * 64) * 768 + h * 96;
  short8 qf[2][3];
#pragma unroll
  for (int mt = 0; mt < 2; ++mt)
#pragma unroll
    for (int es = 0; es < 3; ++es)
      qf[mt][es] = *(const short8*)(Qg + (size_t)(wq * 32 + mt * 16 + ln) * 768 + (es * 4 + quad) * 8);

  const bf16* Kgh = Kt + h * 96;
  const bf16* Vgh = VT + (size_t)h * 96 * 2048;

  // staging maps: K = 64 rows x 12 chunks; V = 96 rows x 8 chunks (3 chunks/thread each)
  int krow[3], koff[3], vrow[3], voff[3];
#pragma unroll
  for (int t = 0; t < 3; ++t) {
    int cid = t * 256 + tid;
    krow[t] = cid / 12; koff[t] = cid % 12;
    vrow[t] = cid >> 3; voff[t] = cid & 7;
  }

  // prologue: load tile 0 into staging registers
  short8 kreg[3], vreg[3];
#pragma unroll
  for (int t = 0; t < 3; ++t) {
    kreg[t] = *(const short8*)(Kgh + (size_t)krow[t] * 768 + koff[t] * 8);
    vreg[t] = *(const short8*)(Vgh + (size_t)vrow[t] * 2048 + voff[t] * 8);
  }

  floatx4 po[2][3] = {};   // O acc: q-rows wq*32+mt*16+quad*4+r, e = ws*48+nt*16+ln
  float psum[2] = {};      // row-sum partial for q = wq*32+mt*16+ln
  const float cexp = 1.4426950408889634f / 9.797958971132712f;  // log2(e)/sqrt(96)

  for (int it = 0; it < 32; ++it) {
    const int s0 = it * 64;
    __syncthreads();  // (1) all waves done reading Ks/Vs of previous tile

    // write staged tile into LDS
#pragma unroll
    for (int t = 0; t < 3; ++t) {
      *(short8*)(&Ks[(krow[t] * 13 + koff[t]) * 8]) = kreg[t];
      *(short8*)(&Vs[(vrow[t] * 9 + voff[t]) * 8]) = vreg[t];
    }
    // issue next tile's coalesced global loads early (hide under compute)
    if (it < 31) {
#pragma unroll
      for (int t = 0; t < 3; ++t) {
        kreg[t] = *(const short8*)(Kgh + (size_t)(s0 + 64 + krow[t]) * 768 + koff[t] * 8);
        vreg[t] = *(const short8*)(Vgh + (size_t)vrow[t] * 2048 + s0 + 64 + voff[t] * 8);
      }
    }
    __syncthreads();  // (2) LDS tile visible

    // QK^T swapped: sacc[mt][ct] = S^T block [s = ws*32+ct*16+quad*4+r][q = wq*32+mt*16+ln]
    floatx4 sacc[2][2] = {};
    const short8* Kv = (const short8*)Ks;
#pragma unroll
    for (int es = 0; es < 3; ++es) {
      short8 kf[2];
#pragma unroll
      for (int ct = 0; ct < 2; ++ct) kf[ct] = Kv[(ws * 32 + ct * 16 + ln) * 13 + es * 4 + quad];
#pragma unroll
      for (int mt = 0; mt < 2; ++mt)
#pragma unroll
        for (int ct = 0; ct < 2; ++ct)
          sacc[mt][ct] = __builtin_amdgcn_mfma_f32_16x16x32_bf16(kf[ct], qf[mt][es], sacc[mt][ct], 0, 0, 0);
    }

    // exp + pack 4 consecutive-s values -> one b64 write per (mt,ct)
#pragma unroll
    for (int mt = 0; mt < 2; ++mt) {
      float rs = 0.f;
#pragma unroll
      for (int ct = 0; ct < 2; ++ct) {
        float p0 = exp2f(sacc[mt][ct][0] * cexp);
        float p1 = exp2f(sacc[mt][ct][1] * cexp);
        float p2 = exp2f(sacc[mt][ct][2] * cexp);
        float p3 = exp2f(sacc[mt][ct][3] * cexp);
        rs += (p0 + p1) + (p2 + p3);
        uint2 uu;
        uu.x = pk2(p0, p1);
        uu.y = pk2(p2, p3);
        *(uint2*)(Ps + (wq * 32 + mt * 16 + ln) * 72 + ws * 32 + ct * 16 + quad * 4) = uu;
      }
      psum[mt] += rs;
    }
    __syncthreads();  // (3) Ps visible (PV needs both s-halves)

    // PV: O[q][e], A = P rows q (full s), B = V^T rows e
    const short8* Pv = (const short8*)Ps;  // 9 chunks/row
    const short8* Vv = (const short8*)Vs;  // 9 chunks/row
#pragma unroll
    for (int ks = 0; ks < 2; ++ks) {
      short8 pa[2];
#pragma unroll
      for (int mt = 0; mt < 2; ++mt) pa[mt] = Pv[(wq * 32 + mt * 16 + ln) * 9 + ks * 4 + quad];
#pragma unroll
      for (int nt = 0; nt < 3; ++nt) {
        short8 vb = Vv[(ws * 48 + nt * 16 + ln) * 9 + ks * 4 + quad];
#pragma unroll
        for (int mt = 0; mt < 2; ++mt)
          po[mt][nt] = __builtin_amdgcn_mfma_f32_16x16x32_bf16(pa[mt], vb, po[mt][nt], 0, 0, 0);
      }
    }
  }

  // ---- row sums: quad-combine in-wave, ws-combine via LDS ----
  float t0 = psum[0], t1 = psum[1];
  t0 += __shfl_xor(t0, 16, 64); t0 += __shfl_xor(t0, 32, 64);
  t1 += __shfl_xor(t1, 16, 64); t1 += __shfl_xor(t1, 32, 64);
  if (lane < 16) {
    Rs[ws][wq * 32 + lane] = t0;
    Rs[ws][wq * 32 + 16 + lane] = t1;
  }
  __syncthreads();

  float linv[2][4];
#pragma unroll
  for (int mt = 0; mt < 2; ++mt)
#pragma unroll
    for (int r = 0; r < 4; ++r) {
      int q = wq * 32 + mt * 16 + quad * 4 + r;
      float v = Rs[0][q] + Rs[1][q];
      linv[mt][r] = 1.f / fmaxf(v, 1e-37f);
    }

  bf16* og = rep + (size_t)(b * 512 + qt * 64) * 768 + h * 96;
#pragma unroll
  for (int mt = 0; mt < 2; ++mt)
#pragma unroll
    for (int nt = 0; nt < 3; ++nt)
#pragma unroll
      for (int r = 0; r < 4; ++r) {
        int row = wq * 32 + mt * 16 + quad * 4 + r;
        int e = ws * 48 + nt * 16 + ln;
        og[(size_t)row * 768 + e] = __float2bfloat16(po[mt][nt][r] * linv[mt][r]);
      }
}

extern "C" void kernel_launch(void* const* d_in, const int* in_sizes, int n_in,
                              void* d_out, int out_size, void* d_ws, size_t ws_size,
                              hipStream_t stream) {
  const float* target = (const float*)d_in[0];  // (8192, 768)
  const float* source = (const float*)d_in[1];  // (2048, 4096)
  const float* Wq = (const float*)d_in[2];
  const float* bq = (const float*)d_in[3];
  const float* Wk = (const float*)d_in[4];
  const float* bk = (const float*)d_in[5];
  const float* Wv = (const float*)d_in[6];
  const float* bv = (const float*)d_in[7];
  const float* Wo = (const float*)d_in[8];
  const float* bo = (const float*)d_in[9];
  float* out = (float*)d_out;                   // (8192, 4096) fp32

  // Round-4 workspace layout (cvt restored; rep overlays src_bf after KV-proj)
  bf16* ws = (bf16*)d_ws;
  bf16* tgt_bf = ws;                    //  6,291,456
  bf16* src_bf = tgt_bf + 6291456;      //  8,388,608
  bf16* WqT = src_bf + 8388608;         //    589,824
  bf16* WkvT = WqT + 589824;            //  6,291,456
  bf16* WoT = WkvT + 6291456;           //  3,145,728
  bf16* Qws = WoT + 3145728;            //  6,291,456
  bf16* Kws = Qws + 6291456;            //  1,572,864
  bf16* VTws = Kws + 1572864;           //  1,572,864
  float* Pkv = (float*)(ws + 34144256); //  NS x 2048*1536 fp32
  const size_t SEG = 2048ull * 1536 * 4;          // 12.58 MB per split-K segment
  const size_t NEED2 = 68288512ull + 2 * SEG;     // 93.5 MB (verified fits in prior rounds)
  bf16* repws = src_bf;                 // overlay: source dead after KV-proj

  cvt_trans<<<24128, 256, 0, stream>>>(target, source, Wq, Wk, Wv, Wo,
                                       tgt_bf, src_bf, WqT, WkvT, WoT);

  if (ws_size >= NEED2) {
    qkv_proj<2><<<768 + 768, 256, 0, stream>>>(tgt_bf, src_bf, WqT, WkvT, bq, Qws, Pkv);
    reduce_kv_both<2><<<dim3(1536, 2), 256, 0, stream>>>(Pkv, bk, bv, Kws, VTws);
  } else {
    qkv_proj<1><<<768 + 384, 256, 0, stream>>>(tgt_bf, src_bf, WqT, WkvT, bq, Qws, Pkv);
    reduce_kv_both<1><<<dim3(1536, 2), 256, 0, stream>>>(Pkv, bk, bv, Kws, VTws);
  }

  // grid.x = h (XCD locality for the per-head K/V slice), grid.y = b*8 + qt
  attn_kernel<<<dim3(8, 128), 256, 0, stream>>>(Qws, Kws, VTws, repws);

  // Wo: 128^2, XCD-chunked block order (A-panels + whole WoT L2-resident per XCD)
  gemm_wo<<<2048, 256, 0, stream>>>(repws, WoT, bo, out);
}